// Round 5
// baseline (140.638 us; speedup 1.0000x reference)
//
#include <hip/hip_runtime.h>
#include <hip/hip_bf16.h>

#define E_EDGES 300000
#define N_NODES 50000
#define BE 512              // edges per block (8 waves x 64)
#define NT 512              // threads per block
#define KC 256              // K-depth per chunk (of 4096)
#define NCHUNK 16
#define CHUNK_BYTES 16384   // 32 v * 256 k * 2B
#define BIAS_OFF 262144     // b2 image (2 KB)
#define W1PK_OFF 264192     // W1 dup-f16 image (3 KB)
#define B1PK_OFF 267264     // b1 dup-f16 image (512 B)

typedef _Float16 h2 __attribute__((ext_vector_type(2)));
typedef _Float16 h8 __attribute__((ext_vector_type(8)));
typedef float f32x16 __attribute__((ext_vector_type(16)));

static __device__ __forceinline__ unsigned short f2h(float f) {
  _Float16 h = (_Float16)f;
  return __builtin_bit_cast(unsigned short, h);
}
static __device__ __forceinline__ h2 cvt2(float a, float b) {
  auto r = __builtin_amdgcn_cvt_pkrtz(a, b);
  return __builtin_bit_cast(h2, r);
}
static __device__ __forceinline__ h2 bc(unsigned u) { return __builtin_bit_cast(h2, u); }
static __device__ __forceinline__ h2 dup_lo(h2 p) { return (h2){p[0], p[0]}; }
static __device__ __forceinline__ h2 dup_hi(h2 p) { return (h2){p[1], p[1]}; }
// A-fragment = hd (broadcast h pair) * 4 packed x pairs -> 4 v_pk_mul_f16
static __device__ __forceinline__ h8 mk4(h2 hd, const h2* p) {
  h2 m0 = hd * p[0], m1 = hd * p[1], m2 = hd * p[2], m3 = hd * p[3];
  return (h8){m0[0], m0[1], m1[0], m1[1], m2[0], m2[1], m3[0], m3[1]};
}
static __device__ __forceinline__ h8 pk4(const h2* p) {
  return (h8){p[0][0], p[0][1], p[1][0], p[1][1], p[2][0], p[2][1], p[3][0], p[3][1]};
}

// ---------------------------------------------------------------------------
// Prep: W2 (flat (4096,32) row-major) -> f16, transposed [v][k] per 256-deep
// chunk, XOR-swizzled ((v&31)<<4 on 16B granules within 512B rows), linear
// images in ws. b2 -> [v][w] f16 image. W1/b1 -> duplicated-f16 u32 images.
// ---------------------------------------------------------------------------
__global__ void prep_w2t(const float* __restrict__ W2, const float* __restrict__ b2,
                         const float* __restrict__ W1, const float* __restrict__ b1,
                         char* __restrict__ ws) {
  int tid = blockIdx.x * 256 + threadIdx.x;
  if (tid < 65536) {                  // 16 chunks * 32 v * 128 k-pairs
    int c   = tid >> 12;
    int rem = tid & 4095;
    int v   = rem >> 7;               // 0..31
    int kp  = rem & 127;              // k-pair within chunk
    int kg2 = c * KC + kp * 2;        // global K index
    unsigned u = (unsigned)f2h(W2[(size_t)kg2 * 32 + v]) |
                 ((unsigned)f2h(W2[(size_t)(kg2 + 1) * 32 + v]) << 16);
    int off = c * CHUNK_BYTES + v * 512 + ((kp * 4) ^ ((v & 31) << 4));
    *(unsigned*)(ws + off) = u;
  } else if (tid < 66048) {           // bias b2: 32 v * 16 w-pairs
    int i  = tid - 65536;
    int v  = i & 31;
    int wp = i >> 5;
    int w  = wp * 2;
    unsigned u = (unsigned)f2h(b2[w * 32 + v]) |
                 ((unsigned)f2h(b2[(w + 1) * 32 + v]) << 16);
    *(unsigned*)(ws + BIAS_OFF + v * 64 + wp * 4) = u;
  } else if (tid < 66816) {           // W1 dup image: 6*128
    int i = tid - 66048;
    unsigned short s = f2h(W1[i]);
    *(unsigned*)(ws + W1PK_OFF + i * 4) = (unsigned)s | ((unsigned)s << 16);
  } else if (tid < 66944) {           // b1 dup image: 128
    int i = tid - 66816;
    unsigned short s = f2h(b1[i]);
    *(unsigned*)(ws + B1PK_OFF + i * 4) = (unsigned)s | ((unsigned)s << 16);
  }
}

// ---------------------------------------------------------------------------
// Fused main (512 edges / 8 waves per block): packed-f16 h recompute ->
// pk_mul A-frags -> f16 MFMA vs LDS-staged W2 chunk -> bias MFMA -> scatter.
// ---------------------------------------------------------------------------
__launch_bounds__(NT, 6)
__global__ void nnconv_main(const float* __restrict__ x,
                            const int* __restrict__ senders,
                            const int* __restrict__ receivers,
                            const float* __restrict__ edge_attr,
                            const char* __restrict__ ws,
                            float* __restrict__ out) {
  __shared__ __align__(16) char w2t[2][CHUNK_BYTES];
  __shared__ int rcv_lds[BE];

  const int t    = threadIdx.x;
  const int wid  = t >> 6;
  const int lane = t & 63;
  const int col  = lane & 31;
  const int hi   = lane >> 5;
  const int E0   = blockIdx.x * BE;

  // ---- issue async stage of chunk 0 (earliest). 512 thr * 16B * 2 = 16 KB
  {
#pragma unroll
    for (int it = 0; it < 2; ++it)
      __builtin_amdgcn_global_load_lds(
          (const __attribute__((address_space(1))) void*)(ws + it * 8192 + t * 16),
          (__attribute__((address_space(3))) void*)(&w2t[0][0] + it * 8192 + t * 16), 16, 0, 0);
  }

  rcv_lds[t] = (E0 + t < E_EDGES) ? receivers[E0 + t] : -1;

  // ---- this lane's two edge rows
  const int el0 = wid * 64 + col;
  const int el1 = el0 + 32;
  const int ge0 = min(E0 + el0, E_EDGES - 1);
  const int ge1 = min(E0 + el1, E_EDGES - 1);

  // ---- edge attrs for BOTH edges, packed (el0 in lo, el1 in hi)
  h2 ea2[6];
  {
    const float2* p0 = (const float2*)(edge_attr + (size_t)ge0 * 6);
    const float2* p1 = (const float2*)(edge_attr + (size_t)ge1 * 6);
    const float2 a0 = p0[0], a1 = p0[1], a2 = p0[2];
    const float2 c0 = p1[0], c1 = p1[1], c2 = p1[2];
    ea2[0] = cvt2(a0.x, c0.x); ea2[1] = cvt2(a0.y, c0.y);
    ea2[2] = cvt2(a1.x, c1.x); ea2[3] = cvt2(a1.y, c1.y);
    ea2[4] = cvt2(a2.x, c2.x); ea2[5] = cvt2(a2.y, c2.y);
  }

  // ---- gather x_j slices, convert to f16 pairs
  const float* row0 = x + (size_t)senders[ge0] * 32;
  const float* row1 = x + (size_t)senders[ge1] * 32;
  float4 fa, fb;
  fa = *(const float4*)(row0 + hi * 8);      fb = *(const float4*)(row0 + hi * 8 + 4);
  const h2 xA0[4] = {cvt2(fa.x, fa.y), cvt2(fa.z, fa.w), cvt2(fb.x, fb.y), cvt2(fb.z, fb.w)};
  fa = *(const float4*)(row0 + 16 + hi * 8); fb = *(const float4*)(row0 + 16 + hi * 8 + 4);
  const h2 xB0[4] = {cvt2(fa.x, fa.y), cvt2(fa.z, fa.w), cvt2(fb.x, fb.y), cvt2(fb.z, fb.w)};
  fa = *(const float4*)(row1 + hi * 8);      fb = *(const float4*)(row1 + hi * 8 + 4);
  const h2 xA1[4] = {cvt2(fa.x, fa.y), cvt2(fa.z, fa.w), cvt2(fb.x, fb.y), cvt2(fb.z, fb.w)};
  fa = *(const float4*)(row1 + 16 + hi * 8); fb = *(const float4*)(row1 + 16 + hi * 8 + 4);
  const h2 xB1[4] = {cvt2(fa.x, fa.y), cvt2(fa.z, fa.w), cvt2(fb.x, fb.y), cvt2(fb.z, fb.w)};

  const unsigned* w1p = (const unsigned*)(ws + W1PK_OFF);
  const unsigned* b1p = (const unsigned*)(ws + B1PK_OFF);

  __syncthreads();   // rcv + chunk0 (barrier drains vmcnt) ready

  f32x16 acc0 = {};
  f32x16 acc1 = {};
  const int swB = (col & 31) << 4;
  int buf = 0;

#pragma unroll 1
  for (int c = 0; c < NCHUNK; ++c) {
    if (c + 1 < NCHUNK) {   // prefetch next chunk into other buffer
      const char* g = ws + (c + 1) * CHUNK_BYTES;
      char* l = &w2t[buf ^ 1][0];
#pragma unroll
      for (int it = 0; it < 2; ++it)
        __builtin_amdgcn_global_load_lds(
            (const __attribute__((address_space(1))) void*)(g + it * 8192 + t * 16),
            (__attribute__((address_space(3))) void*)(l + it * 8192 + t * 16), 16, 0, 0);
    }

    // ---- h for hidden units c*8 .. c*8+7, both edges at once (packed f16)
    h2 hv2[8];
#pragma unroll
    for (int kq = 0; kq < 8; ++kq) hv2[kq] = bc(b1p[c * 8 + kq]);
#pragma unroll
    for (int d = 0; d < 6; ++d) {
#pragma unroll
      for (int kq = 0; kq < 8; ++kq)
        hv2[kq] += ea2[d] * bc(w1p[d * 128 + c * 8 + kq]);
    }
#pragma unroll
    for (int kq = 0; kq < 8; ++kq)
      hv2[kq] = __builtin_elementwise_max(hv2[kq], (h2)(_Float16)0);  // relu

    // ---- 16 K-steps over this chunk
    const char* Bb = &w2t[buf][0] + col * 512;
#pragma unroll
    for (int s = 0; s < 16; ++s) {
      const h8 B = *(const h8*)(Bb + ((s * 32 + hi * 16) ^ swB));
      const int kq = s >> 1;
      const h2 hA = dup_lo(hv2[kq]);
      const h2 hB = dup_hi(hv2[kq]);
      h8 A0, A1;
      if (s & 1) { A0 = mk4(hA, xB0); A1 = mk4(hB, xB1); }
      else       { A0 = mk4(hA, xA0); A1 = mk4(hB, xA1); }
      acc0 = __builtin_amdgcn_mfma_f32_32x32x16_f16(A0, B, acc0, 0, 0, 0);
      acc1 = __builtin_amdgcn_mfma_f32_32x32x16_f16(A1, B, acc1, 0, 0, 0);
    }
    __syncthreads();   // drains prefetch + protects buffer reuse
    buf ^= 1;
  }

  // ---- bias: two extra MFMA K-steps (h == 1), B-frags straight from global
  {
    const char* bb = ws + BIAS_OFF + col * 64;
    const h8 B0 = *(const h8*)(bb + hi * 16);
    const h8 B1 = *(const h8*)(bb + 32 + hi * 16);
    acc0 = __builtin_amdgcn_mfma_f32_32x32x16_f16(pk4(xA0), B0, acc0, 0, 0, 0);
    acc1 = __builtin_amdgcn_mfma_f32_32x32x16_f16(pk4(xA1), B0, acc1, 0, 0, 0);
    acc0 = __builtin_amdgcn_mfma_f32_32x32x16_f16(pk4(xB0), B1, acc0, 0, 0, 0);
    acc1 = __builtin_amdgcn_mfma_f32_32x32x16_f16(pk4(xB1), B1, acc1, 0, 0, 0);
  }

  // ---- scatter: C/D layout col=lane&31, row=(r&3)+8*(r>>2)+4*hi
#pragma unroll
  for (int r = 0; r < 16; ++r) {
    const int row = (r & 3) + 8 * (r >> 2) + 4 * hi;
    const int rcv0 = rcv_lds[wid * 64 + row];
    if (rcv0 >= 0) atomicAdd(out + (size_t)rcv0 * 32 + col, acc0[r]);
    const int rcv1 = rcv_lds[wid * 64 + 32 + row];
    if (rcv1 >= 0) atomicAdd(out + (size_t)rcv1 * 32 + col, acc1[r]);
  }
}

extern "C" void kernel_launch(void* const* d_in, const int* in_sizes, int n_in,
                              void* d_out, int out_size, void* d_ws, size_t ws_size,
                              hipStream_t stream) {
  const float* x         = (const float*)d_in[0];
  const int*   senders   = (const int*)d_in[1];
  const int*   receivers = (const int*)d_in[2];
  const float* edge_attr = (const float*)d_in[3];
  const float* W1        = (const float*)d_in[4];
  const float* b1        = (const float*)d_in[5];
  const float* W2        = (const float*)d_in[6];
  const float* b2        = (const float*)d_in[7];
  float* out = (float*)d_out;
  char*  ws  = (char*)d_ws;

  (void)hipMemsetAsync(out, 0, (size_t)N_NODES * 32 * sizeof(float), stream);
  prep_w2t<<<262, 256, 0, stream>>>(W2, b2, W1, b1, ws);
  nnconv_main<<<(E_EDGES + BE - 1) / BE, NT, 0, stream>>>(
      x, senders, receivers, edge_attr, ws, out);
}

// Round 6
// 106.955 us; speedup vs baseline: 1.3149x; 1.3149x over previous
//
#include <hip/hip_runtime.h>
#include <hip/hip_bf16.h>

#define E_EDGES 300000
#define N_NODES 50000
#define BE 256              // edges per block (4 waves x 64)
#define NCHUNK 16           // 16 chunks x 16 K-steps = 256 steps (K=4096)
#define BIAS_OFF 262144     // bias frag image (2 KB)
#define W1PK_OFF 264192     // W1 dup-f16 image (3 KB)
#define B1PK_OFF 267264     // b1 dup-f16 image (512 B)

typedef _Float16 h2 __attribute__((ext_vector_type(2)));
typedef _Float16 h8 __attribute__((ext_vector_type(8)));
typedef float f32x16 __attribute__((ext_vector_type(16)));

static __device__ __forceinline__ unsigned short f2h(float f) {
  _Float16 h = (_Float16)f;
  return __builtin_bit_cast(unsigned short, h);
}
static __device__ __forceinline__ unsigned pk2(float a, float b) {
  return (unsigned)f2h(a) | ((unsigned)f2h(b) << 16);
}
static __device__ __forceinline__ h2 cvt2(float a, float b) {
  auto r = __builtin_amdgcn_cvt_pkrtz(a, b);
  return __builtin_bit_cast(h2, r);
}
static __device__ __forceinline__ h2 bc(unsigned u) { return __builtin_bit_cast(h2, u); }
static __device__ __forceinline__ h2 dup_lo(h2 p) { return (h2){p[0], p[0]}; }
static __device__ __forceinline__ h2 dup_hi(h2 p) { return (h2){p[1], p[1]}; }
// A-fragment = hd (broadcast h pair) * 4 packed x pairs -> 4 v_pk_mul_f16
static __device__ __forceinline__ h8 mk4(h2 hd, const h2* p) {
  h2 m0 = hd * p[0], m1 = hd * p[1], m2 = hd * p[2], m3 = hd * p[3];
  return (h8){m0[0], m0[1], m1[0], m1[1], m2[0], m2[1], m3[0], m3[1]};
}
static __device__ __forceinline__ h8 pk4(const h2* p) {
  return (h8){p[0][0], p[0][1], p[1][0], p[1][1], p[2][0], p[2][1], p[3][0], p[3][1]};
}

// ---------------------------------------------------------------------------
// Prep: W2 (flat (4096,32) row-major) -> PRE-FRAGMENTED f16 image:
// for K-step s (16 K-values), lane l (= hi*32+col) holds the 8 f16
//   B[k = s*16 + hi*8 + j][v = col],  j = 0..7
// at ws[s*1024 + l*16]. Wave reads = 1KB coalesced, identical across waves.
// Bias b2 -> same fragment form (2 steps, K=w). W1/b1 -> dup-f16 u32 images.
// ---------------------------------------------------------------------------
__global__ void prep_w2t(const float* __restrict__ W2, const float* __restrict__ b2,
                         const float* __restrict__ W1, const float* __restrict__ b1,
                         char* __restrict__ ws) {
  int tid = blockIdx.x * 256 + threadIdx.x;
  if (tid < 65536) {                  // 256 steps * 64 lanes * 4 u32
    int s   = tid >> 8;
    int r   = tid & 255;
    int l   = r >> 2;
    int jp  = r & 3;
    int hi  = l >> 5, col = l & 31;
    int k0  = s * 16 + hi * 8 + jp * 2;
    unsigned u = pk2(W2[(size_t)k0 * 32 + col], W2[(size_t)(k0 + 1) * 32 + col]);
    *(unsigned*)(ws + tid * 4) = u;   // = s*1024 + l*16 + jp*4
  } else if (tid < 66048) {           // bias frag image: 2 steps * 64 lanes * 4 u32
    int i  = tid - 65536;
    int s  = i >> 8;
    int r  = i & 255;
    int l  = r >> 2, jp = r & 3;
    int hi = l >> 5, col = l & 31;
    int w0 = s * 16 + hi * 8 + jp * 2;
    unsigned u = pk2(b2[w0 * 32 + col], b2[(w0 + 1) * 32 + col]);
    *(unsigned*)(ws + BIAS_OFF + i * 4) = u;
  } else if (tid < 66816) {           // W1 dup image: 6*128
    int i = tid - 66048;
    unsigned short s = f2h(W1[i]);
    *(unsigned*)(ws + W1PK_OFF + i * 4) = (unsigned)s | ((unsigned)s << 16);
  } else if (tid < 66944) {           // b1 dup image: 128
    int i = tid - 66816;
    unsigned short s = f2h(b1[i]);
    *(unsigned*)(ws + B1PK_OFF + i * 4) = (unsigned)s | ((unsigned)s << 16);
  }
}

// ---------------------------------------------------------------------------
// Fused main, BARRIER-FREE K-loop: packed-f16 h recompute -> pk_mul A-frags ->
// f16 MFMA with B-frags loaded straight from L1/L2 (W2 image is 256 KB,
// fully cache-resident, same stream for every wave) -> bias MFMA -> scatter.
// ---------------------------------------------------------------------------
__launch_bounds__(256, 4)
__global__ void nnconv_main(const float* __restrict__ x,
                            const int* __restrict__ senders,
                            const int* __restrict__ receivers,
                            const float* __restrict__ edge_attr,
                            const char* __restrict__ ws,
                            float* __restrict__ out) {
  __shared__ int rcv_lds[BE];

  const int t    = threadIdx.x;
  const int wid  = t >> 6;
  const int lane = t & 63;
  const int col  = lane & 31;
  const int hi   = lane >> 5;
  const int E0   = blockIdx.x * BE;

  rcv_lds[t] = (E0 + t < E_EDGES) ? receivers[E0 + t] : -1;

  // ---- this lane's two edge rows
  const int el0 = wid * 64 + col;
  const int el1 = el0 + 32;
  const int ge0 = min(E0 + el0, E_EDGES - 1);
  const int ge1 = min(E0 + el1, E_EDGES - 1);

  // ---- edge attrs for BOTH edges, packed (el0 in lo, el1 in hi)
  h2 ea2[6];
  {
    const float2* p0 = (const float2*)(edge_attr + (size_t)ge0 * 6);
    const float2* p1 = (const float2*)(edge_attr + (size_t)ge1 * 6);
    const float2 a0 = p0[0], a1 = p0[1], a2 = p0[2];
    const float2 c0 = p1[0], c1 = p1[1], c2 = p1[2];
    ea2[0] = cvt2(a0.x, c0.x); ea2[1] = cvt2(a0.y, c0.y);
    ea2[2] = cvt2(a1.x, c1.x); ea2[3] = cvt2(a1.y, c1.y);
    ea2[4] = cvt2(a2.x, c2.x); ea2[5] = cvt2(a2.y, c2.y);
  }

  // ---- gather x_j slices, convert to f16 pairs
  const float* row0 = x + (size_t)senders[ge0] * 32;
  const float* row1 = x + (size_t)senders[ge1] * 32;
  float4 fa, fb;
  fa = *(const float4*)(row0 + hi * 8);      fb = *(const float4*)(row0 + hi * 8 + 4);
  const h2 xA0[4] = {cvt2(fa.x, fa.y), cvt2(fa.z, fa.w), cvt2(fb.x, fb.y), cvt2(fb.z, fb.w)};
  fa = *(const float4*)(row0 + 16 + hi * 8); fb = *(const float4*)(row0 + 16 + hi * 8 + 4);
  const h2 xB0[4] = {cvt2(fa.x, fa.y), cvt2(fa.z, fa.w), cvt2(fb.x, fb.y), cvt2(fb.z, fb.w)};
  fa = *(const float4*)(row1 + hi * 8);      fb = *(const float4*)(row1 + hi * 8 + 4);
  const h2 xA1[4] = {cvt2(fa.x, fa.y), cvt2(fa.z, fa.w), cvt2(fb.x, fb.y), cvt2(fb.z, fb.w)};
  fa = *(const float4*)(row1 + 16 + hi * 8); fb = *(const float4*)(row1 + 16 + hi * 8 + 4);
  const h2 xB1[4] = {cvt2(fa.x, fa.y), cvt2(fa.z, fa.w), cvt2(fb.x, fb.y), cvt2(fb.z, fb.w)};

  const unsigned* w1p = (const unsigned*)(ws + W1PK_OFF);
  const unsigned* b1p = (const unsigned*)(ws + B1PK_OFF);

  __syncthreads();   // rcv_lds ready (the only block-wide barrier)

  f32x16 acc0 = {};
  f32x16 acc1 = {};

#pragma unroll 1
  for (int c = 0; c < NCHUNK; ++c) {
    // ---- h for hidden units c*8 .. c*8+7, both edges at once (packed f16)
    h2 hv2[8];
#pragma unroll
    for (int kq = 0; kq < 8; ++kq) hv2[kq] = bc(b1p[c * 8 + kq]);
#pragma unroll
    for (int d = 0; d < 6; ++d) {
#pragma unroll
      for (int kq = 0; kq < 8; ++kq)
        hv2[kq] += ea2[d] * bc(w1p[d * 128 + c * 8 + kq]);
    }
#pragma unroll
    for (int kq = 0; kq < 8; ++kq)
      hv2[kq] = __builtin_elementwise_max(hv2[kq], (h2)(_Float16)0);  // relu

    // ---- 16 K-steps; B-frags straight from the cache-resident image
    const char* Bp = ws + c * 16384 + (size_t)lane * 16;
#pragma unroll
    for (int s = 0; s < 16; ++s) {
      const h8 B = *(const h8*)(Bp + s * 1024);
      const int kq = s >> 1;
      const h2 hA = dup_lo(hv2[kq]);
      const h2 hB = dup_hi(hv2[kq]);
      h8 A0, A1;
      if (s & 1) { A0 = mk4(hA, xB0); A1 = mk4(hB, xB1); }
      else       { A0 = mk4(hA, xA0); A1 = mk4(hB, xA1); }
      acc0 = __builtin_amdgcn_mfma_f32_32x32x16_f16(A0, B, acc0, 0, 0, 0);
      acc1 = __builtin_amdgcn_mfma_f32_32x32x16_f16(A1, B, acc1, 0, 0, 0);
    }
  }

  // ---- bias: two extra MFMA K-steps (h == 1) from the bias frag image
  {
    const char* bb = ws + BIAS_OFF + (size_t)lane * 16;
    const h8 B0 = *(const h8*)(bb);
    const h8 B1 = *(const h8*)(bb + 1024);
    acc0 = __builtin_amdgcn_mfma_f32_32x32x16_f16(pk4(xA0), B0, acc0, 0, 0, 0);
    acc1 = __builtin_amdgcn_mfma_f32_32x32x16_f16(pk4(xA1), B0, acc1, 0, 0, 0);
    acc0 = __builtin_amdgcn_mfma_f32_32x32x16_f16(pk4(xB0), B1, acc0, 0, 0, 0);
    acc1 = __builtin_amdgcn_mfma_f32_32x32x16_f16(pk4(xB1), B1, acc1, 0, 0, 0);
  }

  // ---- scatter: C/D layout col=lane&31, row=(r&3)+8*(r>>2)+4*hi
#pragma unroll
  for (int r = 0; r < 16; ++r) {
    const int row = (r & 3) + 8 * (r >> 2) + 4 * hi;
    const int rcv0 = rcv_lds[wid * 64 + row];
    if (rcv0 >= 0) atomicAdd(out + (size_t)rcv0 * 32 + col, acc0[r]);
    const int rcv1 = rcv_lds[wid * 64 + 32 + row];
    if (rcv1 >= 0) atomicAdd(out + (size_t)rcv1 * 32 + col, acc1[r]);
  }
}

extern "C" void kernel_launch(void* const* d_in, const int* in_sizes, int n_in,
                              void* d_out, int out_size, void* d_ws, size_t ws_size,
                              hipStream_t stream) {
  const float* x         = (const float*)d_in[0];
  const int*   senders   = (const int*)d_in[1];
  const int*   receivers = (const int*)d_in[2];
  const float* edge_attr = (const float*)d_in[3];
  const float* W1        = (const float*)d_in[4];
  const float* b1        = (const float*)d_in[5];
  const float* W2        = (const float*)d_in[6];
  const float* b2        = (const float*)d_in[7];
  float* out = (float*)d_out;
  char*  ws  = (char*)d_ws;

  (void)hipMemsetAsync(out, 0, (size_t)N_NODES * 32 * sizeof(float), stream);
  prep_w2t<<<262, 256, 0, stream>>>(W2, b2, W1, b1, ws);
  nnconv_main<<<(E_EDGES + BE - 1) / BE, 256, 0, stream>>>(
      x, senders, receivers, edge_attr, ws, out);
}